// Round 4
// baseline (212.636 us; speedup 1.0000x reference)
//
#include <hip/hip_runtime.h>
#include <hip/hip_bf16.h>

// B=16, S=512, N=64, H=768, E_TYPES=9, R_TYPES=10
// out: entity_logits (73728) | entity_repr (786432) | relation_logits (322560), fp32

#define S_LEN 512
#define H_DIM 768
#define NPAIR 2016

typedef __bf16 bf16x8 __attribute__((ext_vector_type(8)));
typedef float f32x4 __attribute__((ext_vector_type(4)));

__device__ __forceinline__ void gload_lds16(const void* g, void* l) {
    __builtin_amdgcn_global_load_lds(
        (const __attribute__((address_space(1))) void*)g,
        (__attribute__((address_space(3))) void*)l, 16, 0, 0);
}

__device__ __forceinline__ ushort f2bf(float x) {
    __hip_bfloat16 h = __float2bfloat16(x);
    return *(ushort*)&h;
}

// ---------------------------------------------------------------------------
// elementwise fp32 -> bf16 cast (float4 in, ushort4 out)
// ---------------------------------------------------------------------------
__global__ __launch_bounds__(256) void cast_k(
    const float* __restrict__ in, ushort* __restrict__ out, int n4)
{
    int i = blockIdx.x * 256 + threadIdx.x;
    const int stride = gridDim.x * 256;
    for (; i < n4; i += stride) {
        float4 v = ((const float4*)in)[i];
        ushort4 o;
        o.x = f2bf(v.x); o.y = f2bf(v.y); o.z = f2bf(v.z); o.w = f2bf(v.w);
        ((ushort4*)out)[i] = o;
    }
}

// ---------------------------------------------------------------------------
// transpose + cast: src[R][C] fp32 -> dst[C][R] bf16 (32x32 LDS tiles)
// ---------------------------------------------------------------------------
__global__ __launch_bounds__(256) void trcast_k(
    const float* __restrict__ src, ushort* __restrict__ dst, int R, int C)
{
    __shared__ float t[32][33];
    const int TR = R >> 5;
    const int br = blockIdx.x % TR, bc = blockIdx.x / TR;
    const int r = threadIdx.x >> 5, c = threadIdx.x & 31;
    #pragma unroll
    for (int p = 0; p < 4; ++p) {
        int rr = r + p * 8;
        t[rr][c] = src[(size_t)(br * 32 + rr) * C + bc * 32 + c];
    }
    __syncthreads();
    #pragma unroll
    for (int p = 0; p < 4; ++p) {
        int rr = r + p * 8;
        dst[(size_t)(bc * 32 + rr) * R + br * 32 + c] = f2bf(t[c][rr]);
    }
}

// ---------------------------------------------------------------------------
// prep for relation MFMA: W2rt[16][768] bf16 (cols>=10 zero) + triu pair table
// ---------------------------------------------------------------------------
__global__ __launch_bounds__(256) void prep_rel_k(
    const float* __restrict__ W2r, ushort* __restrict__ W2rt,
    int* __restrict__ ptab)
{
    int t = blockIdx.x * 256 + threadIdx.x;
    if (t < 16 * 768) {
        int col = t / 768, k = t % 768;
        W2rt[t] = (col < 10) ? f2bf(W2r[k * 10 + col]) : (ushort)0;
    }
    int u = t - 16 * 768;
    if (u >= 0 && u < 4096) {
        int i = u >> 6, j = u & 63;
        if (j > i) {
            int p = i * 63 - i * (i - 1) / 2 + (j - i - 1);
            ptab[p] = (i << 8) | j;
        }
    }
}

// ---------------------------------------------------------------------------
// span mean -> entity_repr (fp32 to d_out, bf16 copy to ws for K4)
// ---------------------------------------------------------------------------
__global__ __launch_bounds__(256) void span_k(
    const float* __restrict__ seq, const int* __restrict__ spans,
    float* __restrict__ eout, ushort* __restrict__ ebf)
{
    const int bn = blockIdx.x;       // 0..1023
    const int b = bn >> 6;
    const int s0 = spans[bn * 2], s1 = spans[bn * 2 + 1];
    int lo = s0 < 0 ? 0 : s0;
    int hi = s1 > S_LEN ? S_LEN : s1;
    int cnt = hi - lo;
    if (cnt < 1) cnt = 1;
    const float inv = 1.f / (float)cnt;
    const int tid = threadIdx.x;
    for (int c = tid; c < H_DIM; c += 256) {
        float acc = 0.f;
        for (int s = lo; s < hi; ++s)
            acc += seq[((size_t)b * S_LEN + s) * H_DIM + c];
        float v = acc * inv;
        eout[(size_t)bn * H_DIM + c] = v;
        ebf[(size_t)bn * H_DIM + c] = f2bf(v);
    }
}

// ---------------------------------------------------------------------------
// bf16 MFMA GEMM (m97 structure): C[M,N] = A[M,K] @ Bt[N,K]^T
// 128x128 tile, BK=32, 4 waves (2x2), each wave 64x64 via 4x4 frags 16x16x32.
// EPI 0: bf16 out = relu(acc + bias[n]);  EPI 1: f32 out = acc.
// ---------------------------------------------------------------------------
template<int EPI>
__global__ __launch_bounds__(256) void mfma_gemm_k(
    const ushort* __restrict__ A, const ushort* __restrict__ Bt,
    const float* __restrict__ bias, void* __restrict__ Cout,
    int M, int N, int K)
{
    __shared__ ushort As[4096];   // [128 rows][32 k] bf16 = 8KB
    __shared__ ushort Bs[4096];   // [128 cols][32 k] bf16 = 8KB

    const int tid = threadIdx.x;
    const int lane = tid & 63, wid = tid >> 6;
    const int wr = wid >> 1, wc = wid & 1;
    const int m0 = blockIdx.y * 128, n0 = blockIdx.x * 128;
    const int fr = lane & 15, kg = lane >> 4;

    const int srow = tid >> 2, skq = (tid & 3) * 8;
    const ushort* ag0 = A + (size_t)(m0 + srow) * K + skq;
    const ushort* ag1 = A + (size_t)(m0 + 64 + srow) * K + skq;
    const ushort* bg0 = Bt + (size_t)(n0 + srow) * K + skq;
    const ushort* bg1 = Bt + (size_t)(n0 + 64 + srow) * K + skq;
    ushort* al0 = &As[tid * 8];
    ushort* al1 = &As[2048 + tid * 8];
    ushort* bl0 = &Bs[tid * 8];
    ushort* bl1 = &Bs[2048 + tid * 8];

    int aoff[4], boff[4];
    #pragma unroll
    for (int i = 0; i < 4; ++i) {
        aoff[i] = (wr * 64 + i * 16 + fr) * 32 + kg * 8;
        boff[i] = (wc * 64 + i * 16 + fr) * 32 + kg * 8;
    }

    f32x4 acc[4][4] = {};

    for (int k0 = 0; k0 < K; k0 += 32) {
        __syncthreads();
        gload_lds16(ag0 + k0, al0);
        gload_lds16(ag1 + k0, al1);
        gload_lds16(bg0 + k0, bl0);
        gload_lds16(bg1 + k0, bl1);
        __syncthreads();
        bf16x8 af[4], bv[4];
        #pragma unroll
        for (int i = 0; i < 4; ++i) af[i] = *(const bf16x8*)&As[aoff[i]];
        #pragma unroll
        for (int i = 0; i < 4; ++i) bv[i] = *(const bf16x8*)&Bs[boff[i]];
        #pragma unroll
        for (int mi = 0; mi < 4; ++mi)
            #pragma unroll
            for (int nj = 0; nj < 4; ++nj)
                acc[mi][nj] = __builtin_amdgcn_mfma_f32_16x16x32_bf16(
                    af[mi], bv[nj], acc[mi][nj], 0, 0, 0);
    }

    if (EPI == 0) {
        __hip_bfloat16* Cb = (__hip_bfloat16*)Cout;
        float bcol[4];
        #pragma unroll
        for (int nj = 0; nj < 4; ++nj) bcol[nj] = bias[n0 + wc * 64 + nj * 16 + fr];
        #pragma unroll
        for (int mi = 0; mi < 4; ++mi)
            #pragma unroll
            for (int j = 0; j < 4; ++j) {
                size_t rb = (size_t)(m0 + wr * 64 + mi * 16 + kg * 4 + j) * N
                          + n0 + wc * 64 + fr;
                #pragma unroll
                for (int nj = 0; nj < 4; ++nj)
                    Cb[rb + nj * 16] = __float2bfloat16(
                        fmaxf(acc[mi][nj][j] + bcol[nj], 0.f));
            }
    } else {
        float* Cf = (float*)Cout;
        #pragma unroll
        for (int mi = 0; mi < 4; ++mi)
            #pragma unroll
            for (int j = 0; j < 4; ++j) {
                size_t rb = (size_t)(m0 + wr * 64 + mi * 16 + kg * 4 + j) * N
                          + n0 + wc * 64 + fr;
                #pragma unroll
                for (int nj = 0; nj < 4; ++nj)
                    Cf[rb + nj * 16] = acc[mi][nj][j];
            }
    }
}

// ---------------------------------------------------------------------------
// entity_logits = H1bf (8192x384 bf16) @ W2e (384x9) + b2e
// ---------------------------------------------------------------------------
__global__ __launch_bounds__(256) void elog_k(
    const ushort* __restrict__ H1, const float* __restrict__ W2e,
    const float* __restrict__ b2e, float* __restrict__ out)
{
    __shared__ float Hs[32][388];
    __shared__ float Wt[9][384];
    const int tid = threadIdx.x;
    const int r0 = blockIdx.x * 32;

    for (int i = tid; i < 32 * 48; i += 256) {
        int row = i / 48, c8 = i % 48;
        uint4 v = *(const uint4*)(H1 + (size_t)(r0 + row) * 384 + c8 * 8);
        const __hip_bfloat16* hp = (const __hip_bfloat16*)&v;
        #pragma unroll
        for (int e = 0; e < 8; ++e) Hs[row][c8 * 8 + e] = __bfloat162float(hp[e]);
    }
    for (int i = tid; i < 3456; i += 256) {
        int k = i / 9, r = i % 9;
        Wt[r][k] = W2e[i];
    }
    __syncthreads();

    for (int o = tid; o < 288; o += 256) {
        int row = o / 9, r = o % 9;
        float acc = 0.f;
        #pragma unroll 4
        for (int k4 = 0; k4 < 96; ++k4) {
            float4 h = *(const float4*)&Hs[row][k4 * 4];
            float4 w = *(const float4*)&Wt[r][k4 * 4];
            acc = fmaf(h.x, w.x, acc); acc = fmaf(h.y, w.y, acc);
            acc = fmaf(h.z, w.z, acc); acc = fmaf(h.w, w.w, acc);
        }
        out[(size_t)(r0 + row) * 9 + r] = acc + b2e[r];
    }
}

// ---------------------------------------------------------------------------
// relation logits via MFMA. Block = 256 consecutive pairs (126 blocks).
// Per 32-k chunk: build hidden[256][32] bf16 in LDS (swizzled), then
// mfma(hidden, W2rt) accumulate. Epilogue writes out[p*10 + col].
// ---------------------------------------------------------------------------
__global__ __launch_bounds__(256) void relmm_k(
    const float* __restrict__ UV,     // [1024][1536]: U | V
    const float* __restrict__ b1r,    // [768]
    const ushort* __restrict__ W2rt,  // [16][768] bf16, cols>=10 zero
    const float* __restrict__ b2r,    // [10]
    const int* __restrict__ ptab,     // [2016]: (i<<8)|j in triu order
    float* __restrict__ out)          // [32256][10]
{
    __shared__ ushort Hs[256 * 32];   // 16KB, [pair][32k] with slot swizzle

    const int tid = threadIdx.x;
    const int lane = tid & 63, wid = tid >> 6;
    const int fr = lane & 15, kg = lane >> 4;
    const int p0 = blockIdx.x * 256;

    // build mapping: thread -> (ks = k-octet, pl = pair-lane), 4 pairs via q
    const int ks = tid & 3, pl = tid >> 2;
    size_t uoff[4], voff[4];
    #pragma unroll
    for (int q = 0; q < 4; ++q) {
        int p = p0 + q * 64 + pl;
        unsigned bb = (unsigned)p / 2016u;
        unsigned pp = (unsigned)p - bb * 2016u;
        int ij = ptab[pp];
        int ei = ij >> 8, ej = ij & 255;
        uoff[q] = ((size_t)(bb * 64 + ei)) * 1536;
        voff[q] = ((size_t)(bb * 64 + ej)) * 1536 + 768;
    }
    const int wslot = (ks + ((pl >> 1) & 3)) & 3;  // (pair>>1)&3 == (pl>>1)&3

    f32x4 acc[4] = {};

    for (int c = 0; c < 24; ++c) {
        const int k0 = c * 32, kk = k0 + ks * 8;
        __syncthreads();   // prev chunk's MFMA reads done
        float4 bb0 = *(const float4*)(b1r + kk);
        float4 bb1 = *(const float4*)(b1r + kk + 4);
        #pragma unroll
        for (int q = 0; q < 4; ++q) {
            float4 u0 = *(const float4*)(UV + uoff[q] + kk);
            float4 u1 = *(const float4*)(UV + uoff[q] + kk + 4);
            float4 v0 = *(const float4*)(UV + voff[q] + kk);
            float4 v1 = *(const float4*)(UV + voff[q] + kk + 4);
            ushort h[8];
            h[0] = f2bf(fmaxf(u0.x + v0.x + bb0.x, 0.f));
            h[1] = f2bf(fmaxf(u0.y + v0.y + bb0.y, 0.f));
            h[2] = f2bf(fmaxf(u0.z + v0.z + bb0.z, 0.f));
            h[3] = f2bf(fmaxf(u0.w + v0.w + bb0.w, 0.f));
            h[4] = f2bf(fmaxf(u1.x + v1.x + bb1.x, 0.f));
            h[5] = f2bf(fmaxf(u1.y + v1.y + bb1.y, 0.f));
            h[6] = f2bf(fmaxf(u1.z + v1.z + bb1.z, 0.f));
            h[7] = f2bf(fmaxf(u1.w + v1.w + bb1.w, 0.f));
            int pair = q * 64 + pl;
            *(uint4*)((char*)Hs + pair * 64 + wslot * 16) = *(uint4*)h;
        }
        __syncthreads();   // hidden chunk visible
        bf16x8 bv = *(const bf16x8*)(W2rt + fr * 768 + k0 + kg * 8);
        #pragma unroll
        for (int f = 0; f < 4; ++f) {
            int pr = wid * 64 + f * 16 + fr;
            int slot = (kg + ((pr >> 1) & 3)) & 3;
            bf16x8 av = *(const bf16x8*)((const char*)Hs + pr * 64 + slot * 16);
            acc[f] = __builtin_amdgcn_mfma_f32_16x16x32_bf16(av, bv, acc[f], 0, 0, 0);
        }
    }

    // D layout: col = fr (B-col), row-in-frag = kg*4 + j (A-row)
    const float bias = (fr < 10) ? b2r[fr] : 0.f;
    if (fr < 10) {
        #pragma unroll
        for (int f = 0; f < 4; ++f)
            #pragma unroll
            for (int j = 0; j < 4; ++j) {
                int p = p0 + wid * 64 + f * 16 + kg * 4 + j;
                out[(size_t)p * 10 + fr] = acc[f][j] + bias;
            }
    }
}

// ---------------------------------------------------------------------------
extern "C" void kernel_launch(void* const* d_in, const int* in_sizes, int n_in,
                              void* d_out, int out_size, void* d_ws, size_t ws_size,
                              hipStream_t stream)
{
    const float* seq   = (const float*)d_in[0];
    const int*   spans = (const int*)d_in[2];
    const float* W1e   = (const float*)d_in[3];
    const float* b1e   = (const float*)d_in[4];
    const float* W2e   = (const float*)d_in[5];
    const float* b2e   = (const float*)d_in[6];
    const float* W1r   = (const float*)d_in[7];
    const float* b1r   = (const float*)d_in[8];
    const float* W2r   = (const float*)d_in[9];
    const float* b2r   = (const float*)d_in[10];

    float* out  = (float*)d_out;
    float* elog = out;
    float* erep = out + 73728;
    float* rlog = out + 73728 + 786432;

    // ws layout (bytes); UV aliases seq_bf (seq_bf dead after K1, K4 runs later)
    char* ws = (char*)d_ws;
    ushort* seq_bf  = (ushort*)ws;                    // 8192*768*2  = 12,582,912
    float*  UV      = (float*)ws;                     // 1024*1536*4 =  6,291,456 (alias)
    ushort* W1et    = (ushort*)(ws + 12582912);       //  384*768*2  =    589,824
    ushort* W1rt    = (ushort*)(ws + 13172736);       // 1536*768*2  =  2,359,296
    ushort* erep_bf = (ushort*)(ws + 15532032);       // 1024*768*2  =  1,572,864
    ushort* H1bf    = (ushort*)(ws + 17104896);       // 8192*384*2  =  6,291,456
    ushort* W2rt    = (ushort*)(ws + 23396352);       //   16*768*2  =     24,576
    int*    ptab    = (int*)   (ws + 23420928);       //   2016*4    =      8,064
    // total 23,428,992 B

    // casts / transposes / prep
    cast_k<<<2048, 256, 0, stream>>>(seq, seq_bf, (8192 * 768) / 4);
    trcast_k<<<288, 256, 0, stream>>>(W1e, W1et, 768, 384);
    trcast_k<<<576, 256, 0, stream>>>(W1r, W1rt, 768, 768);
    trcast_k<<<576, 256, 0, stream>>>(W1r + 768 * 768, W1rt + 768 * 768, 768, 768);
    prep_rel_k<<<64, 256, 0, stream>>>(W2r, W2rt, ptab);
    // entity_repr (fp32 exact) + bf16 copy
    span_k<<<1024, 256, 0, stream>>>(seq, spans, erep, erep_bf);
    // H1 = relu(seq @ W1e + b1e) -> bf16
    mfma_gemm_k<0><<<dim3(3, 64), 256, 0, stream>>>(seq_bf, W1et, b1e, H1bf, 8192, 384, 768);
    // entity_logits
    elog_k<<<256, 256, 0, stream>>>(H1bf, W2e, b2e, elog);
    // UV = erep @ [W1r_top | W1r_bot]
    mfma_gemm_k<1><<<dim3(12, 8), 256, 0, stream>>>(erep_bf, W1rt, nullptr, UV, 1024, 1536, 768);
    // relation_logits via MFMA
    relmm_k<<<126, 256, 0, stream>>>(UV, b1r, W2rt, b2r, ptab, rlog);
}

// Round 6
// 165.827 us; speedup vs baseline: 1.2823x; 1.2823x over previous
//
#include <hip/hip_runtime.h>
#include <hip/hip_bf16.h>

// B=16, S=512, N=64, H=768, E_TYPES=9, R_TYPES=10
// out: entity_logits (73728) | entity_repr (786432) | relation_logits (322560), fp32

#define S_LEN 512
#define H_DIM 768
#define NPAIR 2016

typedef __bf16 bf16x8 __attribute__((ext_vector_type(8)));
typedef float f32x4 __attribute__((ext_vector_type(4)));

__device__ __forceinline__ void gload_lds16(const void* g, void* l) {
    __builtin_amdgcn_global_load_lds(
        (const __attribute__((address_space(1))) void*)g,
        (__attribute__((address_space(3))) void*)l, 16, 0, 0);
}

__device__ __forceinline__ ushort f2bf(float x) {
    __hip_bfloat16 h = __float2bfloat16(x);
    return *(ushort*)&h;
}

// ---------------------------------------------------------------------------
// K_A: mega prep kernel. blockIdx ranges:
//   [0,1024)      span mean -> erep (fp32) + erep_bf
//   [1024,1312)   trcast W1e (768x384)
//   [1312,1888)   trcast W1r top half (768x768)
//   [1888,2464)   trcast W1r bottom half (768x768)
//   [2464,2552)   W2rt (16x768, pad) + W2et (16x384, pad) + ptab
//   [2552,2680)   rlog init with b2r (grid-stride)
//   [2680,3704)   cast seq -> seq_bf (grid-stride float4)
// ---------------------------------------------------------------------------
__global__ __launch_bounds__(256) void prep_all_k(
    const float* __restrict__ seq, const int* __restrict__ spans,
    const float* __restrict__ W1e, const float* __restrict__ W1r,
    const float* __restrict__ W2e, const float* __restrict__ W2r,
    const float* __restrict__ b2r,
    float* __restrict__ erep, ushort* __restrict__ erep_bf,
    ushort* __restrict__ W1et, ushort* __restrict__ W1rt,
    ushort* __restrict__ W2et, ushort* __restrict__ W2rt,
    int* __restrict__ ptab, float* __restrict__ rlog,
    ushort* __restrict__ seq_bf)
{
    __shared__ float t[32][33];
    const int bid = blockIdx.x, tid = threadIdx.x;

    if (bid < 1024) {
        // ---- span mean ----
        const int bn = bid, b = bn >> 6;
        const int s0 = spans[bn * 2], s1 = spans[bn * 2 + 1];
        int lo = s0 < 0 ? 0 : s0;
        int hi = s1 > S_LEN ? S_LEN : s1;
        int cnt = hi - lo;
        if (cnt < 1) cnt = 1;
        const float inv = 1.f / (float)cnt;
        for (int c = tid; c < H_DIM; c += 256) {
            float acc = 0.f;
            for (int s = lo; s < hi; ++s)
                acc += seq[((size_t)b * S_LEN + s) * H_DIM + c];
            float v = acc * inv;
            erep[(size_t)bn * H_DIM + c] = v;
            erep_bf[(size_t)bn * H_DIM + c] = f2bf(v);
        }
    } else if (bid < 2464) {
        // ---- transpose+cast jobs ----
        const float* src; ushort* dst; int b2, C;
        if (bid < 1312)      { b2 = bid - 1024; src = W1e; dst = W1et; C = 384; }
        else if (bid < 1888) { b2 = bid - 1312; src = W1r; dst = W1rt; C = 768; }
        else                 { b2 = bid - 1888; src = W1r + 768 * 768; dst = W1rt + 768 * 768; C = 768; }
        const int br = b2 % 24, bc = b2 / 24;   // R=768 always -> TR=24
        const int r = tid >> 5, c = tid & 31;
        #pragma unroll
        for (int p = 0; p < 4; ++p) {
            int rr = r + p * 8;
            t[rr][c] = src[(size_t)(br * 32 + rr) * C + bc * 32 + c];
        }
        __syncthreads();
        #pragma unroll
        for (int p = 0; p < 4; ++p) {
            int rr = r + p * 8;
            dst[(size_t)(bc * 32 + rr) * 768 + br * 32 + c] = f2bf(t[c][rr]);
        }
    } else if (bid < 2552) {
        // ---- small weights + pair table ----
        int idx = (bid - 2464) * 256 + tid;     // [0, 22528)
        if (idx < 12288) {                       // W2rt[16][768]
            int col = idx / 768, k = idx % 768;
            W2rt[idx] = (col < 10) ? f2bf(W2r[k * 10 + col]) : (ushort)0;
        } else if (idx < 18432) {                // W2et[16][384]
            int u = idx - 12288;
            int col = u / 384, k = u % 384;
            W2et[u] = (col < 9) ? f2bf(W2e[k * 9 + col]) : (ushort)0;
        } else {                                 // ptab
            int u = idx - 18432;                 // < 4096
            int i = u >> 6, j = u & 63;
            if (j > i) {
                int p = i * 63 - i * (i - 1) / 2 + (j - i - 1);
                ptab[p] = (i << 8) | j;
            }
        }
    } else if (bid < 2680) {
        // ---- rlog init with b2r ----
        for (int n = (bid - 2552) * 256 + tid; n < 16 * NPAIR * 10; n += 128 * 256)
            rlog[n] = b2r[n % 10];
    } else {
        // ---- cast seq -> bf16 ----
        for (int i = (bid - 2680) * 256 + tid; i < (8192 * 768) / 4; i += 1024 * 256) {
            float4 v = ((const float4*)seq)[i];
            ushort4 o;
            o.x = f2bf(v.x); o.y = f2bf(v.y); o.z = f2bf(v.z); o.w = f2bf(v.w);
            ((ushort4*)seq_bf)[i] = o;
        }
    }
}

// ---------------------------------------------------------------------------
// bf16 MFMA GEMM: C[M,N] = A[M,K] @ Bt[N,K]^T.  Tile MT x 128, BK=32,
// 4 waves (2x2); wave tile (MT/2) x 64 via (MT/32) x 4 frags of 16x16x32.
// EPI 0: bf16 out = relu(acc + bias[n]);  EPI 1: f32 out = acc.
// ---------------------------------------------------------------------------
template<int MT, int EPI>
__global__ __launch_bounds__(256) void mfma_gemm_k(
    const ushort* __restrict__ A, const ushort* __restrict__ Bt,
    const float* __restrict__ bias, void* __restrict__ Cout,
    int M, int N, int K)
{
    constexpr int MI = MT / 32;          // M-frags per wave
    __shared__ ushort As[MT * 32];
    __shared__ ushort Bs[4096];

    const int tid = threadIdx.x;
    const int lane = tid & 63, wid = tid >> 6;
    const int wr = wid >> 1, wc = wid & 1;
    const int m0 = blockIdx.y * MT, n0 = blockIdx.x * 128;
    const int fr = lane & 15, kg = lane >> 4;

    const int srow = tid >> 2, skq = (tid & 3) * 8;
    const ushort* ag0 = A + (size_t)(m0 + srow) * K + skq;
    const ushort* ag1 = A + (size_t)(m0 + 64 + srow) * K + skq;   // MT==128 only
    const ushort* bg0 = Bt + (size_t)(n0 + srow) * K + skq;
    const ushort* bg1 = Bt + (size_t)(n0 + 64 + srow) * K + skq;
    ushort* al0 = &As[tid * 8];
    ushort* al1 = &As[2048 + tid * 8];
    ushort* bl0 = &Bs[tid * 8];
    ushort* bl1 = &Bs[2048 + tid * 8];

    int aoff[MI], boff[4];
    #pragma unroll
    for (int i = 0; i < MI; ++i)
        aoff[i] = (wr * (MT / 2) + i * 16 + fr) * 32 + kg * 8;
    #pragma unroll
    for (int i = 0; i < 4; ++i)
        boff[i] = (wc * 64 + i * 16 + fr) * 32 + kg * 8;

    f32x4 acc[MI][4] = {};

    for (int k0 = 0; k0 < K; k0 += 32) {
        __syncthreads();
        gload_lds16(ag0 + k0, al0);
        if constexpr (MT == 128) gload_lds16(ag1 + k0, al1);
        gload_lds16(bg0 + k0, bl0);
        gload_lds16(bg1 + k0, bl1);
        __syncthreads();
        bf16x8 af[MI], bv[4];
        #pragma unroll
        for (int i = 0; i < MI; ++i) af[i] = *(const bf16x8*)&As[aoff[i]];
        #pragma unroll
        for (int i = 0; i < 4; ++i) bv[i] = *(const bf16x8*)&Bs[boff[i]];
        #pragma unroll
        for (int mi = 0; mi < MI; ++mi)
            #pragma unroll
            for (int nj = 0; nj < 4; ++nj)
                acc[mi][nj] = __builtin_amdgcn_mfma_f32_16x16x32_bf16(
                    af[mi], bv[nj], acc[mi][nj], 0, 0, 0);
    }

    // C/D: col = lane&15, row = (lane>>4)*4 + reg
    if (EPI == 0) {
        __hip_bfloat16* Cb = (__hip_bfloat16*)Cout;
        float bcol[4];
        #pragma unroll
        for (int nj = 0; nj < 4; ++nj) bcol[nj] = bias[n0 + wc * 64 + nj * 16 + fr];
        #pragma unroll
        for (int mi = 0; mi < MI; ++mi)
            #pragma unroll
            for (int j = 0; j < 4; ++j) {
                size_t rb = (size_t)(m0 + wr * (MT / 2) + mi * 16 + kg * 4 + j) * N
                          + n0 + wc * 64 + fr;
                #pragma unroll
                for (int nj = 0; nj < 4; ++nj)
                    Cb[rb + nj * 16] = __float2bfloat16(
                        fmaxf(acc[mi][nj][j] + bcol[nj], 0.f));
            }
    } else {
        float* Cf = (float*)Cout;
        #pragma unroll
        for (int mi = 0; mi < MI; ++mi)
            #pragma unroll
            for (int j = 0; j < 4; ++j) {
                size_t rb = (size_t)(m0 + wr * (MT / 2) + mi * 16 + kg * 4 + j) * N
                          + n0 + wc * 64 + fr;
                #pragma unroll
                for (int nj = 0; nj < 4; ++nj)
                    Cf[rb + nj * 16] = acc[mi][nj][j];
            }
    }
}

// ---------------------------------------------------------------------------
// entity_logits: H1bf (8192x384) @ W2et(16x384,padded)^T + b2e.
// Per wave: 16 rows, barrier-free, A-frag built straight from global.
// ---------------------------------------------------------------------------
__global__ __launch_bounds__(256) void elogmm_k(
    const ushort* __restrict__ H1, const ushort* __restrict__ W2et,
    const float* __restrict__ b2e, float* __restrict__ out)
{
    const int tid = threadIdx.x;
    const int lane = tid & 63, wid = tid >> 6;
    const int fr = lane & 15, kg = lane >> 4;
    const int rbase = blockIdx.x * 64 + wid * 16;

    f32x4 acc = {};
    #pragma unroll
    for (int c = 0; c < 12; ++c) {
        const int kk = c * 32 + kg * 8;
        bf16x8 av = *(const bf16x8*)(H1 + (size_t)(rbase + fr) * 384 + kk);
        bf16x8 bv = *(const bf16x8*)(W2et + fr * 384 + kk);
        acc = __builtin_amdgcn_mfma_f32_16x16x32_bf16(av, bv, acc, 0, 0, 0);
    }
    if (fr < 9) {
        const float bias = b2e[fr];
        #pragma unroll
        for (int j = 0; j < 4; ++j)
            out[(size_t)(rbase + kg * 4 + j) * 9 + fr] = acc[j] + bias;
    }
}

// ---------------------------------------------------------------------------
// relation logits, barrier-free: each lane builds the A-frag element
// (row = pair = fr, k-octet = kg) of hidden = relu(U_i + V_j + b1r) in
// registers, MFMA vs W2rt. K split in 2 halves (atomicAdd, rlog pre-init
// with b2r). Grid 252 = 126 pair-blocks x 2 k-halves.
// ---------------------------------------------------------------------------
__global__ __launch_bounds__(256) void relmm_k(
    const float* __restrict__ UV,     // [1024][1536]: U | V
    const float* __restrict__ b1r,    // [768]
    const ushort* __restrict__ W2rt,  // [16][768] bf16, cols>=10 zero
    const int* __restrict__ ptab,     // [2016]: (i<<8)|j triu order
    float* __restrict__ rlog)         // [32256][10], pre-init b2r
{
    const int tid = threadIdx.x;
    const int lane = tid & 63, wid = tid >> 6;
    const int fr = lane & 15, kg = lane >> 4;
    const int pb = blockIdx.x % 126, kb = blockIdx.x / 126;
    const int p0 = pb * 256;

    size_t uoff[4], voff[4];
    #pragma unroll
    for (int q = 0; q < 4; ++q) {
        int p = p0 + wid * 64 + q * 16 + fr;
        unsigned bb = (unsigned)p / 2016u;
        unsigned pp = (unsigned)p - bb * 2016u;
        int ij = ptab[pp];
        uoff[q] = ((size_t)(bb * 64 + (ij >> 8))) * 1536;
        voff[q] = ((size_t)(bb * 64 + (ij & 255))) * 1536 + 768;
    }

    f32x4 acc[4] = {};

    for (int c = kb * 12; c < kb * 12 + 12; ++c) {
        const int k0 = c * 32, kk = k0 + kg * 8;
        const bf16x8 bv = *(const bf16x8*)(W2rt + fr * 768 + kk);
        const float4 bb0 = *(const float4*)(b1r + kk);
        const float4 bb1 = *(const float4*)(b1r + kk + 4);
        #pragma unroll
        for (int q = 0; q < 4; ++q) {
            float4 u0 = *(const float4*)(UV + uoff[q] + kk);
            float4 u1 = *(const float4*)(UV + uoff[q] + kk + 4);
            float4 v0 = *(const float4*)(UV + voff[q] + kk);
            float4 v1 = *(const float4*)(UV + voff[q] + kk + 4);
            ushort h[8];
            h[0] = f2bf(fmaxf(u0.x + v0.x + bb0.x, 0.f));
            h[1] = f2bf(fmaxf(u0.y + v0.y + bb0.y, 0.f));
            h[2] = f2bf(fmaxf(u0.z + v0.z + bb0.z, 0.f));
            h[3] = f2bf(fmaxf(u0.w + v0.w + bb0.w, 0.f));
            h[4] = f2bf(fmaxf(u1.x + v1.x + bb1.x, 0.f));
            h[5] = f2bf(fmaxf(u1.y + v1.y + bb1.y, 0.f));
            h[6] = f2bf(fmaxf(u1.z + v1.z + bb1.z, 0.f));
            h[7] = f2bf(fmaxf(u1.w + v1.w + bb1.w, 0.f));
            bf16x8 av = *(bf16x8*)h;
            acc[q] = __builtin_amdgcn_mfma_f32_16x16x32_bf16(av, bv, acc[q], 0, 0, 0);
        }
    }

    // C/D: col = fr (logit), rows kg*4+j within the 16-pair frag
    if (fr < 10) {
        #pragma unroll
        for (int q = 0; q < 4; ++q)
            #pragma unroll
            for (int j = 0; j < 4; ++j) {
                int p = p0 + wid * 64 + q * 16 + kg * 4 + j;
                atomicAdd(&rlog[(size_t)p * 10 + fr], acc[q][j]);
            }
    }
}

// ---------------------------------------------------------------------------
extern "C" void kernel_launch(void* const* d_in, const int* in_sizes, int n_in,
                              void* d_out, int out_size, void* d_ws, size_t ws_size,
                              hipStream_t stream)
{
    const float* seq   = (const float*)d_in[0];
    const int*   spans = (const int*)d_in[2];
    const float* W1e   = (const float*)d_in[3];
    const float* b1e   = (const float*)d_in[4];
    const float* W2e   = (const float*)d_in[5];
    const float* b2e   = (const float*)d_in[6];
    const float* W1r   = (const float*)d_in[7];
    const float* b1r   = (const float*)d_in[8];
    const float* W2r   = (const float*)d_in[9];
    const float* b2r   = (const float*)d_in[10];

    float* out  = (float*)d_out;
    float* elog = out;
    float* erep = out + 73728;
    float* rlog = out + 73728 + 786432;

    // ws layout; UV aliases seq_bf (seq_bf dead after gemm<0>)
    char* ws = (char*)d_ws;
    ushort* seq_bf  = (ushort*)ws;                    // 12,582,912
    float*  UV      = (float*)ws;                     //  6,291,456 (alias)
    ushort* W1et    = (ushort*)(ws + 12582912);       //    589,824
    ushort* W1rt    = (ushort*)(ws + 13172736);       //  2,359,296
    ushort* erep_bf = (ushort*)(ws + 15532032);       //  1,572,864
    ushort* H1bf    = (ushort*)(ws + 17104896);       //  6,291,456
    ushort* W2rt    = (ushort*)(ws + 23396352);       //     24,576
    int*    ptab    = (int*)   (ws + 23420928);       //      8,064
    ushort* W2et    = (ushort*)(ws + 23428992);       //     12,288
    // total 23,441,280 B

    // K_A: all prep (span, transposes, casts, small weights, rlog init)
    prep_all_k<<<3704, 256, 0, stream>>>(seq, spans, W1e, W1r, W2e, W2r, b2r,
                                         erep, erep_bf, W1et, W1rt, W2et, W2rt,
                                         ptab, rlog, seq_bf);
    // K_B: H1 = relu(seq @ W1e + b1e) -> bf16   (8192x384x768)
    mfma_gemm_k<64, 0><<<dim3(3, 128), 256, 0, stream>>>(
        seq_bf, W1et, b1e, H1bf, 8192, 384, 768);
    // K_C: entity_logits = H1 @ W2e + b2e
    elogmm_k<<<128, 256, 0, stream>>>(H1bf, W2et, b2e, elog);
    // K_D: UV = erep @ [W1r_top | W1r_bot]      (1024x1536x768)
    mfma_gemm_k<64, 1><<<dim3(12, 16), 256, 0, stream>>>(
        erep_bf, W1rt, nullptr, UV, 1024, 1536, 768);
    // K_E: relation_logits (atomic accumulate onto b2r init)
    relmm_k<<<252, 256, 0, stream>>>(UV, b1r, W2rt, ptab, rlog);
}

// Round 7
// 165.671 us; speedup vs baseline: 1.2835x; 1.0009x over previous
//
#include <hip/hip_runtime.h>
#include <hip/hip_bf16.h>

// B=16, S=512, N=64, H=768, E_TYPES=9, R_TYPES=10
// out: entity_logits (73728) | entity_repr (786432) | relation_logits (322560), fp32

#define S_LEN 512
#define H_DIM 768
#define NPAIR 2016

typedef __bf16 bf16x8 __attribute__((ext_vector_type(8)));
typedef float f32x4 __attribute__((ext_vector_type(4)));

__device__ __forceinline__ void gload_lds16(const void* g, void* l) {
    __builtin_amdgcn_global_load_lds(
        (const __attribute__((address_space(1))) void*)g,
        (__attribute__((address_space(3))) void*)l, 16, 0, 0);
}

__device__ __forceinline__ ushort f2bf(float x) {
    __hip_bfloat16 h = __float2bfloat16(x);
    return *(ushort*)&h;
}

// ---------------------------------------------------------------------------
// K_A: mega prep kernel. blockIdx ranges:
//   [0,1024)      span mean -> erep (fp32) + erep_bf
//   [1024,1312)   trcast W1e (768x384)
//   [1312,1888)   trcast W1r top half (768x768)
//   [1888,2464)   trcast W1r bottom half (768x768)
//   [2464,2552)   W2rt (16x768, pad) + W2et (16x384, pad) + ptab
//   [2552,2680)   rlog init with b2r (grid-stride)
//   [2680,3704)   cast seq -> seq_bf (grid-stride float4)
// ---------------------------------------------------------------------------
__global__ __launch_bounds__(256) void prep_all_k(
    const float* __restrict__ seq, const int* __restrict__ spans,
    const float* __restrict__ W1e, const float* __restrict__ W1r,
    const float* __restrict__ W2e, const float* __restrict__ W2r,
    const float* __restrict__ b2r,
    float* __restrict__ erep, ushort* __restrict__ erep_bf,
    ushort* __restrict__ W1et, ushort* __restrict__ W1rt,
    ushort* __restrict__ W2et, ushort* __restrict__ W2rt,
    int* __restrict__ ptab, float* __restrict__ rlog,
    ushort* __restrict__ seq_bf)
{
    __shared__ float t[32][33];
    const int bid = blockIdx.x, tid = threadIdx.x;

    if (bid < 1024) {
        // ---- span mean ----
        const int bn = bid, b = bn >> 6;
        const int s0 = spans[bn * 2], s1 = spans[bn * 2 + 1];
        int lo = s0 < 0 ? 0 : s0;
        int hi = s1 > S_LEN ? S_LEN : s1;
        int cnt = hi - lo;
        if (cnt < 1) cnt = 1;
        const float inv = 1.f / (float)cnt;
        for (int c = tid; c < H_DIM; c += 256) {
            float acc = 0.f;
            for (int s = lo; s < hi; ++s)
                acc += seq[((size_t)b * S_LEN + s) * H_DIM + c];
            float v = acc * inv;
            erep[(size_t)bn * H_DIM + c] = v;
            erep_bf[(size_t)bn * H_DIM + c] = f2bf(v);
        }
    } else if (bid < 2464) {
        // ---- transpose+cast jobs ----
        const float* src; ushort* dst; int b2, C;
        if (bid < 1312)      { b2 = bid - 1024; src = W1e; dst = W1et; C = 384; }
        else if (bid < 1888) { b2 = bid - 1312; src = W1r; dst = W1rt; C = 768; }
        else                 { b2 = bid - 1888; src = W1r + 768 * 768; dst = W1rt + 768 * 768; C = 768; }
        const int br = b2 % 24, bc = b2 / 24;   // R=768 always -> TR=24
        const int r = tid >> 5, c = tid & 31;
        #pragma unroll
        for (int p = 0; p < 4; ++p) {
            int rr = r + p * 8;
            t[rr][c] = src[(size_t)(br * 32 + rr) * C + bc * 32 + c];
        }
        __syncthreads();
        #pragma unroll
        for (int p = 0; p < 4; ++p) {
            int rr = r + p * 8;
            dst[(size_t)(bc * 32 + rr) * 768 + br * 32 + c] = f2bf(t[c][rr]);
        }
    } else if (bid < 2552) {
        // ---- small weights + pair table ----
        int idx = (bid - 2464) * 256 + tid;     // [0, 22528)
        if (idx < 12288) {                       // W2rt[16][768]
            int col = idx / 768, k = idx % 768;
            W2rt[idx] = (col < 10) ? f2bf(W2r[k * 10 + col]) : (ushort)0;
        } else if (idx < 18432) {                // W2et[16][384]
            int u = idx - 12288;
            int col = u / 384, k = u % 384;
            W2et[u] = (col < 9) ? f2bf(W2e[k * 9 + col]) : (ushort)0;
        } else {                                 // ptab
            int u = idx - 18432;                 // < 4096
            int i = u >> 6, j = u & 63;
            if (j > i) {
                int p = i * 63 - i * (i - 1) / 2 + (j - i - 1);
                ptab[p] = (i << 8) | j;
            }
        }
    } else if (bid < 2680) {
        // ---- rlog init with b2r ----
        for (int n = (bid - 2552) * 256 + tid; n < 16 * NPAIR * 10; n += 128 * 256)
            rlog[n] = b2r[n % 10];
    } else {
        // ---- cast seq -> bf16 ----
        for (int i = (bid - 2680) * 256 + tid; i < (8192 * 768) / 4; i += 1024 * 256) {
            float4 v = ((const float4*)seq)[i];
            ushort4 o;
            o.x = f2bf(v.x); o.y = f2bf(v.y); o.z = f2bf(v.z); o.w = f2bf(v.w);
            ((ushort4*)seq_bf)[i] = o;
        }
    }
}

// ---------------------------------------------------------------------------
// bf16 MFMA GEMM, 2-phase double-buffered (T3-minimal): C = A[M,K] @ Bt[N,K]^T
// Tile MT x 128, BK=32, 4 waves (2x2); wave tile (MT/2) x 64.
// Per k-step: stage next tile -> ds_read cur -> MFMA -> vmcnt(0)+barrier.
// Loads fly during the compute phase instead of being drained at issue.
// EPI 0: bf16 out = relu(acc + bias[n]);  EPI 1: f32 out = acc.
// ---------------------------------------------------------------------------
template<int MT, int EPI>
__global__ __launch_bounds__(256) void mfma_gemm_k(
    const ushort* __restrict__ A, const ushort* __restrict__ Bt,
    const float* __restrict__ bias, void* __restrict__ Cout,
    int M, int N, int K)
{
    constexpr int MI = MT / 32;          // M-frags per wave
    __shared__ ushort As[2][MT * 32];
    __shared__ ushort Bs[2][4096];

    const int tid = threadIdx.x;
    const int lane = tid & 63, wid = tid >> 6;
    const int wr = wid >> 1, wc = wid & 1;
    const int m0 = blockIdx.y * MT, n0 = blockIdx.x * 128;
    const int fr = lane & 15, kg = lane >> 4;

    const int srow = tid >> 2, skq = (tid & 3) * 8;
    const ushort* ag0 = A + (size_t)(m0 + srow) * K + skq;
    const ushort* ag1 = A + (size_t)(m0 + 64 + srow) * K + skq;   // MT==128 only
    const ushort* bg0 = Bt + (size_t)(n0 + srow) * K + skq;
    const ushort* bg1 = Bt + (size_t)(n0 + 64 + srow) * K + skq;

    int aoff[MI], boff[4];
    #pragma unroll
    for (int i = 0; i < MI; ++i)
        aoff[i] = (wr * (MT / 2) + i * 16 + fr) * 32 + kg * 8;
    #pragma unroll
    for (int i = 0; i < 4; ++i)
        boff[i] = (wc * 64 + i * 16 + fr) * 32 + kg * 8;

    f32x4 acc[MI][4] = {};

    const int nsteps = K / 32;

    // prologue: stage tile 0 into buf 0
    gload_lds16(ag0, &As[0][tid * 8]);
    if constexpr (MT == 128) gload_lds16(ag1, &As[0][2048 + tid * 8]);
    gload_lds16(bg0, &Bs[0][tid * 8]);
    gload_lds16(bg1, &Bs[0][2048 + tid * 8]);
    asm volatile("s_waitcnt vmcnt(0)");
    __syncthreads();

    int cur = 0;
    for (int t = 0; t < nsteps - 1; ++t) {
        const int kn = (t + 1) * 32;
        // stage next tile into cur^1 (in flight during compute below)
        gload_lds16(ag0 + kn, &As[cur ^ 1][tid * 8]);
        if constexpr (MT == 128) gload_lds16(ag1 + kn, &As[cur ^ 1][2048 + tid * 8]);
        gload_lds16(bg0 + kn, &Bs[cur ^ 1][tid * 8]);
        gload_lds16(bg1 + kn, &Bs[cur ^ 1][2048 + tid * 8]);
        // compute cur
        bf16x8 af[MI], bv[4];
        #pragma unroll
        for (int i = 0; i < MI; ++i) af[i] = *(const bf16x8*)&As[cur][aoff[i]];
        #pragma unroll
        for (int i = 0; i < 4; ++i) bv[i] = *(const bf16x8*)&Bs[cur][boff[i]];
        #pragma unroll
        for (int mi = 0; mi < MI; ++mi)
            #pragma unroll
            for (int nj = 0; nj < 4; ++nj)
                acc[mi][nj] = __builtin_amdgcn_mfma_f32_16x16x32_bf16(
                    af[mi], bv[nj], acc[mi][nj], 0, 0, 0);
        asm volatile("s_waitcnt vmcnt(0)");
        __syncthreads();
        cur ^= 1;
    }
    // epilogue k-step: compute last tile (no prefetch)
    {
        bf16x8 af[MI], bv[4];
        #pragma unroll
        for (int i = 0; i < MI; ++i) af[i] = *(const bf16x8*)&As[cur][aoff[i]];
        #pragma unroll
        for (int i = 0; i < 4; ++i) bv[i] = *(const bf16x8*)&Bs[cur][boff[i]];
        #pragma unroll
        for (int mi = 0; mi < MI; ++mi)
            #pragma unroll
            for (int nj = 0; nj < 4; ++nj)
                acc[mi][nj] = __builtin_amdgcn_mfma_f32_16x16x32_bf16(
                    af[mi], bv[nj], acc[mi][nj], 0, 0, 0);
    }

    // C/D: col = lane&15, row = (lane>>4)*4 + reg
    if (EPI == 0) {
        __hip_bfloat16* Cb = (__hip_bfloat16*)Cout;
        float bcol[4];
        #pragma unroll
        for (int nj = 0; nj < 4; ++nj) bcol[nj] = bias[n0 + wc * 64 + nj * 16 + fr];
        #pragma unroll
        for (int mi = 0; mi < MI; ++mi)
            #pragma unroll
            for (int j = 0; j < 4; ++j) {
                size_t rb = (size_t)(m0 + wr * (MT / 2) + mi * 16 + kg * 4 + j) * N
                          + n0 + wc * 64 + fr;
                #pragma unroll
                for (int nj = 0; nj < 4; ++nj)
                    Cb[rb + nj * 16] = __float2bfloat16(
                        fmaxf(acc[mi][nj][j] + bcol[nj], 0.f));
            }
    } else {
        float* Cf = (float*)Cout;
        #pragma unroll
        for (int mi = 0; mi < MI; ++mi)
            #pragma unroll
            for (int j = 0; j < 4; ++j) {
                size_t rb = (size_t)(m0 + wr * (MT / 2) + mi * 16 + kg * 4 + j) * N
                          + n0 + wc * 64 + fr;
                #pragma unroll
                for (int nj = 0; nj < 4; ++nj)
                    Cf[rb + nj * 16] = acc[mi][nj][j];
            }
    }
}

// ---------------------------------------------------------------------------
// entity_logits: H1bf (8192x384) @ W2et(16x384,padded)^T + b2e.
// Per wave: 16 rows, barrier-free, A-frag built straight from global.
// ---------------------------------------------------------------------------
__global__ __launch_bounds__(256) void elogmm_k(
    const ushort* __restrict__ H1, const ushort* __restrict__ W2et,
    const float* __restrict__ b2e, float* __restrict__ out)
{
    const int tid = threadIdx.x;
    const int lane = tid & 63, wid = tid >> 6;
    const int fr = lane & 15, kg = lane >> 4;
    const int rbase = blockIdx.x * 64 + wid * 16;

    f32x4 acc = {};
    #pragma unroll
    for (int c = 0; c < 12; ++c) {
        const int kk = c * 32 + kg * 8;
        bf16x8 av = *(const bf16x8*)(H1 + (size_t)(rbase + fr) * 384 + kk);
        bf16x8 bv = *(const bf16x8*)(W2et + fr * 384 + kk);
        acc = __builtin_amdgcn_mfma_f32_16x16x32_bf16(av, bv, acc, 0, 0, 0);
    }
    if (fr < 9) {
        const float bias = b2e[fr];
        #pragma unroll
        for (int j = 0; j < 4; ++j)
            out[(size_t)(rbase + kg * 4 + j) * 9 + fr] = acc[j] + bias;
    }
}

// ---------------------------------------------------------------------------
// relation logits, barrier-free: each lane builds the A-frag element
// (row = pair = fr, k-octet = kg) of hidden = relu(U_i + V_j + b1r) in
// registers, MFMA vs W2rt. K split in 3 (atomicAdd, rlog pre-init b2r).
// Grid 378 = 126 pair-blocks x 3 k-thirds (8 chunks each).
// ---------------------------------------------------------------------------
__global__ __launch_bounds__(256) void relmm_k(
    const float* __restrict__ UV,     // [1024][1536]: U | V
    const float* __restrict__ b1r,    // [768]
    const ushort* __restrict__ W2rt,  // [16][768] bf16, cols>=10 zero
    const int* __restrict__ ptab,     // [2016]: (i<<8)|j triu order
    float* __restrict__ rlog)         // [32256][10], pre-init b2r
{
    const int tid = threadIdx.x;
    const int lane = tid & 63, wid = tid >> 6;
    const int fr = lane & 15, kg = lane >> 4;
    const int pb = blockIdx.x % 126, kb = blockIdx.x / 126;
    const int p0 = pb * 256;

    size_t uoff[4], voff[4];
    #pragma unroll
    for (int q = 0; q < 4; ++q) {
        int p = p0 + wid * 64 + q * 16 + fr;
        unsigned bb = (unsigned)p / 2016u;
        unsigned pp = (unsigned)p - bb * 2016u;
        int ij = ptab[pp];
        uoff[q] = ((size_t)(bb * 64 + (ij >> 8))) * 1536;
        voff[q] = ((size_t)(bb * 64 + (ij & 255))) * 1536 + 768;
    }

    f32x4 acc[4] = {};

    for (int c = kb * 8; c < kb * 8 + 8; ++c) {
        const int k0 = c * 32, kk = k0 + kg * 8;
        const bf16x8 bv = *(const bf16x8*)(W2rt + fr * 768 + kk);
        const float4 bb0 = *(const float4*)(b1r + kk);
        const float4 bb1 = *(const float4*)(b1r + kk + 4);
        #pragma unroll
        for (int q = 0; q < 4; ++q) {
            float4 u0 = *(const float4*)(UV + uoff[q] + kk);
            float4 u1 = *(const float4*)(UV + uoff[q] + kk + 4);
            float4 v0 = *(const float4*)(UV + voff[q] + kk);
            float4 v1 = *(const float4*)(UV + voff[q] + kk + 4);
            ushort h[8];
            h[0] = f2bf(fmaxf(u0.x + v0.x + bb0.x, 0.f));
            h[1] = f2bf(fmaxf(u0.y + v0.y + bb0.y, 0.f));
            h[2] = f2bf(fmaxf(u0.z + v0.z + bb0.z, 0.f));
            h[3] = f2bf(fmaxf(u0.w + v0.w + bb0.w, 0.f));
            h[4] = f2bf(fmaxf(u1.x + v1.x + bb1.x, 0.f));
            h[5] = f2bf(fmaxf(u1.y + v1.y + bb1.y, 0.f));
            h[6] = f2bf(fmaxf(u1.z + v1.z + bb1.z, 0.f));
            h[7] = f2bf(fmaxf(u1.w + v1.w + bb1.w, 0.f));
            bf16x8 av = *(bf16x8*)h;
            acc[q] = __builtin_amdgcn_mfma_f32_16x16x32_bf16(av, bv, acc[q], 0, 0, 0);
        }
    }

    // C/D: col = fr (logit), rows kg*4+j within the 16-pair frag
    if (fr < 10) {
        #pragma unroll
        for (int q = 0; q < 4; ++q)
            #pragma unroll
            for (int j = 0; j < 4; ++j) {
                int p = p0 + wid * 64 + q * 16 + kg * 4 + j;
                atomicAdd(&rlog[(size_t)p * 10 + fr], acc[q][j]);
            }
    }
}

// ---------------------------------------------------------------------------
extern "C" void kernel_launch(void* const* d_in, const int* in_sizes, int n_in,
                              void* d_out, int out_size, void* d_ws, size_t ws_size,
                              hipStream_t stream)
{
    const float* seq   = (const float*)d_in[0];
    const int*   spans = (const int*)d_in[2];
    const float* W1e   = (const float*)d_in[3];
    const float* b1e   = (const float*)d_in[4];
    const float* W2e   = (const float*)d_in[5];
    const float* b2e   = (const float*)d_in[6];
    const float* W1r   = (const float*)d_in[7];
    const float* b1r   = (const float*)d_in[8];
    const float* W2r   = (const float*)d_in[9];
    const float* b2r   = (const float*)d_in[10];

    float* out  = (float*)d_out;
    float* elog = out;
    float* erep = out + 73728;
    float* rlog = out + 73728 + 786432;

    // ws layout; UV aliases seq_bf (seq_bf dead after gemm<0>)
    char* ws = (char*)d_ws;
    ushort* seq_bf  = (ushort*)ws;                    // 12,582,912
    float*  UV      = (float*)ws;                     //  6,291,456 (alias)
    ushort* W1et    = (ushort*)(ws + 12582912);       //    589,824
    ushort* W1rt    = (ushort*)(ws + 13172736);       //  2,359,296
    ushort* erep_bf = (ushort*)(ws + 15532032);       //  1,572,864
    ushort* H1bf    = (ushort*)(ws + 17104896);       //  6,291,456
    ushort* W2rt    = (ushort*)(ws + 23396352);       //     24,576
    int*    ptab    = (int*)   (ws + 23420928);       //      8,064
    ushort* W2et    = (ushort*)(ws + 23428992);       //     12,288
    // total 23,441,280 B

    // K_A: all prep (span, transposes, casts, small weights, rlog init)
    prep_all_k<<<3704, 256, 0, stream>>>(seq, spans, W1e, W1r, W2e, W2r, b2r,
                                         erep, erep_bf, W1et, W1rt, W2et, W2rt,
                                         ptab, rlog, seq_bf);
    // K_B: H1 = relu(seq @ W1e + b1e) -> bf16   (8192x384x768)
    mfma_gemm_k<64, 0><<<dim3(3, 128), 256, 0, stream>>>(
        seq_bf, W1et, b1e, H1bf, 8192, 384, 768);
    // K_C: entity_logits = H1 @ W2e + b2e
    elogmm_k<<<128, 256, 0, stream>>>(H1bf, W2et, b2e, elog);
    // K_D: UV = erep @ [W1r_top | W1r_bot]      (1024x1536x768)
    mfma_gemm_k<64, 1><<<dim3(12, 16), 256, 0, stream>>>(
        erep_bf, W1rt, nullptr, UV, 1024, 1536, 768);
    // K_E: relation_logits (atomic accumulate onto b2r init)
    relmm_k<<<378, 256, 0, stream>>>(UV, b1r, W2rt, ptab, rlog);
}

// Round 9
// 150.413 us; speedup vs baseline: 1.4137x; 1.1014x over previous
//
#include <hip/hip_runtime.h>
#include <hip/hip_bf16.h>

// B=16, S=512, N=64, H=768, E_TYPES=9, R_TYPES=10
// out: entity_logits (73728) | entity_repr (786432) | relation_logits (322560), fp32

#define S_LEN 512
#define H_DIM 768
#define NPAIR 2016

typedef __bf16 bf16x8 __attribute__((ext_vector_type(8)));
typedef float f32x4 __attribute__((ext_vector_type(4)));

__device__ __forceinline__ void gload_lds16(const void* g, void* l) {
    __builtin_amdgcn_global_load_lds(
        (const __attribute__((address_space(1))) void*)g,
        (__attribute__((address_space(3))) void*)l, 16, 0, 0);
}

__device__ __forceinline__ ushort f2bf(float x) {
    __hip_bfloat16 h = __float2bfloat16(x);
    return *(ushort*)&h;
}

// ---------------------------------------------------------------------------
// K_A: mega prep kernel. blockIdx ranges:
//   [0,1024)      span mean -> erep (fp32) + erep_bf
//   [1024,1312)   trcast W1e (768x384)
//   [1312,1888)   trcast W1r top half (768x768)
//   [1888,2464)   trcast W1r bottom half (768x768)
//   [2464,2552)   W2rt (16x768, pad) + W2et (16x384, pad) + ptab
//   [2552,2680)   rlog init with b2r (grid-stride)
//   [2680,3704)   cast seq -> seq_bf (grid-stride float4)
// ---------------------------------------------------------------------------
__global__ __launch_bounds__(256) void prep_all_k(
    const float* __restrict__ seq, const int* __restrict__ spans,
    const float* __restrict__ W1e, const float* __restrict__ W1r,
    const float* __restrict__ W2e, const float* __restrict__ W2r,
    const float* __restrict__ b2r,
    float* __restrict__ erep, ushort* __restrict__ erep_bf,
    ushort* __restrict__ W1et, ushort* __restrict__ W1rt,
    ushort* __restrict__ W2et, ushort* __restrict__ W2rt,
    int* __restrict__ ptab, float* __restrict__ rlog,
    ushort* __restrict__ seq_bf)
{
    __shared__ float t[32][33];
    const int bid = blockIdx.x, tid = threadIdx.x;

    if (bid < 1024) {
        // ---- span mean ----
        const int bn = bid, b = bn >> 6;
        const int s0 = spans[bn * 2], s1 = spans[bn * 2 + 1];
        int lo = s0 < 0 ? 0 : s0;
        int hi = s1 > S_LEN ? S_LEN : s1;
        int cnt = hi - lo;
        if (cnt < 1) cnt = 1;
        const float inv = 1.f / (float)cnt;
        for (int c = tid; c < H_DIM; c += 256) {
            float acc = 0.f;
            for (int s = lo; s < hi; ++s)
                acc += seq[((size_t)b * S_LEN + s) * H_DIM + c];
            float v = acc * inv;
            erep[(size_t)bn * H_DIM + c] = v;
            erep_bf[(size_t)bn * H_DIM + c] = f2bf(v);
        }
    } else if (bid < 2464) {
        // ---- transpose+cast jobs ----
        const float* src; ushort* dst; int b2, C;
        if (bid < 1312)      { b2 = bid - 1024; src = W1e; dst = W1et; C = 384; }
        else if (bid < 1888) { b2 = bid - 1312; src = W1r; dst = W1rt; C = 768; }
        else                 { b2 = bid - 1888; src = W1r + 768 * 768; dst = W1rt + 768 * 768; C = 768; }
        const int br = b2 % 24, bc = b2 / 24;   // R=768 always -> TR=24
        const int r = tid >> 5, c = tid & 31;
        #pragma unroll
        for (int p = 0; p < 4; ++p) {
            int rr = r + p * 8;
            t[rr][c] = src[(size_t)(br * 32 + rr) * C + bc * 32 + c];
        }
        __syncthreads();
        #pragma unroll
        for (int p = 0; p < 4; ++p) {
            int rr = r + p * 8;
            dst[(size_t)(bc * 32 + rr) * 768 + br * 32 + c] = f2bf(t[c][rr]);
        }
    } else if (bid < 2552) {
        // ---- small weights + pair table ----
        int idx = (bid - 2464) * 256 + tid;     // [0, 22528)
        if (idx < 12288) {                       // W2rt[16][768]
            int col = idx / 768, k = idx % 768;
            W2rt[idx] = (col < 10) ? f2bf(W2r[k * 10 + col]) : (ushort)0;
        } else if (idx < 18432) {                // W2et[16][384]
            int u = idx - 12288;
            int col = u / 384, k = u % 384;
            W2et[u] = (col < 9) ? f2bf(W2e[k * 9 + col]) : (ushort)0;
        } else {                                 // ptab
            int u = idx - 18432;                 // < 4096
            int i = u >> 6, j = u & 63;
            if (j > i) {
                int p = i * 63 - i * (i - 1) / 2 + (j - i - 1);
                ptab[p] = (i << 8) | j;
            }
        }
    } else if (bid < 2680) {
        // ---- rlog init with b2r ----
        for (int n = (bid - 2552) * 256 + tid; n < 16 * NPAIR * 10; n += 128 * 256)
            rlog[n] = b2r[n % 10];
    } else {
        // ---- cast seq -> bf16 ----
        for (int i = (bid - 2680) * 256 + tid; i < (8192 * 768) / 4; i += 1024 * 256) {
            float4 v = ((const float4*)seq)[i];
            ushort4 o;
            o.x = f2bf(v.x); o.y = f2bf(v.y); o.z = f2bf(v.z); o.w = f2bf(v.w);
            ((ushort4*)seq_bf)[i] = o;
        }
    }
}

// ---------------------------------------------------------------------------
// GEMM body: C = A[M,K] @ Bt[N,K]^T, tile 64x128, BK=32, 4 waves (2x2),
// wave tile 32x64 (2x4 frags 16x16x32). 4-deep counted-vmcnt pipeline:
// raw s_barrier (no vmcnt drain) + manual s_waitcnt vmcnt(6/3/0) +
// sched_barrier fence. 3 gload_lds per tile -> steady wait = 3*(D-2) = 6.
// EPI 0: bf16 out = relu(acc + bias[n]);  EPI 1: f32 out = acc.
// ---------------------------------------------------------------------------
template<int EPI>
__device__ __forceinline__ void gemm_body(
    const ushort* __restrict__ A, const ushort* __restrict__ Bt,
    const float* __restrict__ bias, void* __restrict__ Cout,
    int bx, int by, int N, int K, ushort* As, ushort* Bs)
{
    const int tid = threadIdx.x;
    const int lane = tid & 63, wid = tid >> 6;
    const int wr = wid >> 1, wc = wid & 1;
    const int m0 = by * 64, n0 = bx * 128;
    const int fr = lane & 15, kg = lane >> 4;

    const int srow = tid >> 2, skq = (tid & 3) * 8;
    const ushort* ag0 = A + (size_t)(m0 + srow) * K + skq;
    const ushort* bg0 = Bt + (size_t)(n0 + srow) * K + skq;
    const ushort* bg1 = Bt + (size_t)(n0 + 64 + srow) * K + skq;

    int aoff[2], boff[4];
    #pragma unroll
    for (int i = 0; i < 2; ++i)
        aoff[i] = (wr * 32 + i * 16 + fr) * 32 + kg * 8;
    #pragma unroll
    for (int i = 0; i < 4; ++i)
        boff[i] = (wc * 64 + i * 16 + fr) * 32 + kg * 8;

    const int nsteps = K / 32;

    auto STAGE = [&](int kt, int buf) {
        const int kn = kt * 32;
        gload_lds16(ag0 + kn, As + buf * 2048 + tid * 8);
        gload_lds16(bg0 + kn, Bs + buf * 4096 + tid * 8);
        gload_lds16(bg1 + kn, Bs + buf * 4096 + 2048 + tid * 8);
    };

    // prologue: tiles 0,1,2 in flight
    STAGE(0, 0);
    STAGE(1, 1);
    STAGE(2, 2);

    f32x4 acc[2][4] = {};

    for (int t = 0; t < nsteps; ++t) {
        if (t < nsteps - 2)       asm volatile("s_waitcnt vmcnt(6)" ::: "memory");
        else if (t == nsteps - 2) asm volatile("s_waitcnt vmcnt(3)" ::: "memory");
        else                      asm volatile("s_waitcnt vmcnt(0)" ::: "memory");
        __builtin_amdgcn_s_barrier();          // raw: no implicit vmcnt drain
        __builtin_amdgcn_sched_barrier(0);     // fence: nothing hoists above
        if (t + 3 < nsteps) STAGE(t + 3, (t + 3) & 3);
        const int buf = t & 3;
        bf16x8 af[2], bv[4];
        #pragma unroll
        for (int i = 0; i < 2; ++i) af[i] = *(const bf16x8*)&As[buf * 2048 + aoff[i]];
        #pragma unroll
        for (int i = 0; i < 4; ++i) bv[i] = *(const bf16x8*)&Bs[buf * 4096 + boff[i]];
        #pragma unroll
        for (int mi = 0; mi < 2; ++mi)
            #pragma unroll
            for (int nj = 0; nj < 4; ++nj)
                acc[mi][nj] = __builtin_amdgcn_mfma_f32_16x16x32_bf16(
                    af[mi], bv[nj], acc[mi][nj], 0, 0, 0);
    }

    // C/D: col = lane&15, row = (lane>>4)*4 + reg
    if (EPI == 0) {
        __hip_bfloat16* Cb = (__hip_bfloat16*)Cout;
        float bcol[4];
        #pragma unroll
        for (int nj = 0; nj < 4; ++nj) bcol[nj] = bias[n0 + wc * 64 + nj * 16 + fr];
        #pragma unroll
        for (int mi = 0; mi < 2; ++mi)
            #pragma unroll
            for (int j = 0; j < 4; ++j) {
                size_t rb = (size_t)(m0 + wr * 32 + mi * 16 + kg * 4 + j) * N
                          + n0 + wc * 64 + fr;
                #pragma unroll
                for (int nj = 0; nj < 4; ++nj)
                    Cb[rb + nj * 16] = __float2bfloat16(
                        fmaxf(acc[mi][nj][j] + bcol[nj], 0.f));
            }
    } else {
        float* Cf = (float*)Cout;
        #pragma unroll
        for (int mi = 0; mi < 2; ++mi)
            #pragma unroll
            for (int j = 0; j < 4; ++j) {
                size_t rb = (size_t)(m0 + wr * 32 + mi * 16 + kg * 4 + j) * N
                          + n0 + wc * 64 + fr;
                #pragma unroll
                for (int nj = 0; nj < 4; ++nj)
                    Cf[rb + nj * 16] = acc[mi][nj][j];
            }
    }
}

// ---------------------------------------------------------------------------
// K_B: fused independent GEMMs in one launch.
//   bid [0,384):   H1bf = relu(seq_bf @ W1et^T + b1e)   (8192x384x768)
//   bid [384,576): UV   = erep_bf @ W1rt^T              (1024x1536x768)
// ---------------------------------------------------------------------------
__global__ __launch_bounds__(256) void gemm2_k(
    const ushort* __restrict__ seq_bf, const ushort* __restrict__ W1et,
    const float* __restrict__ b1e, ushort* __restrict__ H1bf,
    const ushort* __restrict__ erep_bf, const ushort* __restrict__ W1rt,
    float* __restrict__ UV)
{
    __shared__ ushort As[4 * 2048];   // 16 KB
    __shared__ ushort Bs[4 * 4096];   // 32 KB
    const int bid = blockIdx.x;
    if (bid < 384) {
        gemm_body<0>(seq_bf, W1et, b1e, H1bf, bid % 3, bid / 3, 384, 768, As, Bs);
    } else {
        const int b2 = bid - 384;
        gemm_body<1>(erep_bf, W1rt, nullptr, UV, b2 % 12, b2 / 12, 1536, 768, As, Bs);
    }
}

// ---------------------------------------------------------------------------
// K_C: fused consumers in one launch.
//   bid [0,378):   relation logits (barrier-free reg-built A-frag MFMA,
//                  K split x3, atomicAdd onto b2r-pre-inited rlog)
//   bid [378,506): entity_logits = H1bf @ W2et^T + b2e (barrier-free MFMA)
// ---------------------------------------------------------------------------
__global__ __launch_bounds__(256) void post_k(
    const float* __restrict__ UV, const float* __restrict__ b1r,
    const ushort* __restrict__ W2rt, const int* __restrict__ ptab,
    float* __restrict__ rlog,
    const ushort* __restrict__ H1, const ushort* __restrict__ W2et,
    const float* __restrict__ b2e, float* __restrict__ elog)
{
    const int tid = threadIdx.x;
    const int lane = tid & 63, wid = tid >> 6;
    const int fr = lane & 15, kg = lane >> 4;
    const int bid = blockIdx.x;

    if (bid < 378) {
        // ---- relation logits ----
        const int pb = bid % 126, kb = bid / 126;
        const int p0 = pb * 256;

        size_t uoff[4], voff[4];
        #pragma unroll
        for (int q = 0; q < 4; ++q) {
            int p = p0 + wid * 64 + q * 16 + fr;
            unsigned bb = (unsigned)p / 2016u;
            unsigned pp = (unsigned)p - bb * 2016u;
            int ij = ptab[pp];
            uoff[q] = ((size_t)(bb * 64 + (ij >> 8))) * 1536;
            voff[q] = ((size_t)(bb * 64 + (ij & 255))) * 1536 + 768;
        }

        f32x4 acc[4] = {};

        for (int c = kb * 8; c < kb * 8 + 8; ++c) {
            const int k0 = c * 32, kk = k0 + kg * 8;
            const bf16x8 bv = *(const bf16x8*)(W2rt + fr * 768 + kk);
            const float4 bb0 = *(const float4*)(b1r + kk);
            const float4 bb1 = *(const float4*)(b1r + kk + 4);
            #pragma unroll
            for (int q = 0; q < 4; ++q) {
                float4 u0 = *(const float4*)(UV + uoff[q] + kk);
                float4 u1 = *(const float4*)(UV + uoff[q] + kk + 4);
                float4 v0 = *(const float4*)(UV + voff[q] + kk);
                float4 v1 = *(const float4*)(UV + voff[q] + kk + 4);
                ushort h[8];
                h[0] = f2bf(fmaxf(u0.x + v0.x + bb0.x, 0.f));
                h[1] = f2bf(fmaxf(u0.y + v0.y + bb0.y, 0.f));
                h[2] = f2bf(fmaxf(u0.z + v0.z + bb0.z, 0.f));
                h[3] = f2bf(fmaxf(u0.w + v0.w + bb0.w, 0.f));
                h[4] = f2bf(fmaxf(u1.x + v1.x + bb1.x, 0.f));
                h[5] = f2bf(fmaxf(u1.y + v1.y + bb1.y, 0.f));
                h[6] = f2bf(fmaxf(u1.z + v1.z + bb1.z, 0.f));
                h[7] = f2bf(fmaxf(u1.w + v1.w + bb1.w, 0.f));
                bf16x8 av = *(bf16x8*)h;
                acc[q] = __builtin_amdgcn_mfma_f32_16x16x32_bf16(av, bv, acc[q], 0, 0, 0);
            }
        }

        if (fr < 10) {
            #pragma unroll
            for (int q = 0; q < 4; ++q)
                #pragma unroll
                for (int j = 0; j < 4; ++j) {
                    int p = p0 + wid * 64 + q * 16 + kg * 4 + j;
                    atomicAdd(&rlog[(size_t)p * 10 + fr], acc[q][j]);
                }
        }
    } else {
        // ---- entity logits ----
        const int rbase = (bid - 378) * 64 + wid * 16;
        f32x4 acc = {};
        #pragma unroll
        for (int c = 0; c < 12; ++c) {
            const int kk = c * 32 + kg * 8;
            bf16x8 av = *(const bf16x8*)(H1 + (size_t)(rbase + fr) * 384 + kk);
            bf16x8 bv = *(const bf16x8*)(W2et + fr * 384 + kk);
            acc = __builtin_amdgcn_mfma_f32_16x16x32_bf16(av, bv, acc, 0, 0, 0);
        }
        if (fr < 9) {
            const float bias = b2e[fr];
            #pragma unroll
            for (int j = 0; j < 4; ++j)
                elog[(size_t)(rbase + kg * 4 + j) * 9 + fr] = acc[j] + bias;
        }
    }
}

// ---------------------------------------------------------------------------
extern "C" void kernel_launch(void* const* d_in, const int* in_sizes, int n_in,
                              void* d_out, int out_size, void* d_ws, size_t ws_size,
                              hipStream_t stream)
{
    const float* seq   = (const float*)d_in[0];
    const int*   spans = (const int*)d_in[2];
    const float* W1e   = (const float*)d_in[3];
    const float* b1e   = (const float*)d_in[4];
    const float* W2e   = (const float*)d_in[5];
    const float* b2e   = (const float*)d_in[6];
    const float* W1r   = (const float*)d_in[7];
    const float* b1r   = (const float*)d_in[8];
    const float* W2r   = (const float*)d_in[9];
    const float* b2r   = (const float*)d_in[10];

    float* out  = (float*)d_out;
    float* elog = out;
    float* erep = out + 73728;
    float* rlog = out + 73728 + 786432;

    // ws layout; UV and seq_bf both live during gemm2_k -> separate buffers.
    char* ws = (char*)d_ws;
    ushort* seq_bf  = (ushort*)ws;                    // 12,582,912
    ushort* W1et    = (ushort*)(ws + 12582912);       //    589,824
    ushort* W1rt    = (ushort*)(ws + 13172736);       //  2,359,296
    ushort* erep_bf = (ushort*)(ws + 15532032);       //  1,572,864
    ushort* H1bf    = (ushort*)(ws + 17104896);       //  6,291,456
    ushort* W2rt    = (ushort*)(ws + 23396352);       //     24,576
    int*    ptab    = (int*)   (ws + 23420928);       //      8,064
    ushort* W2et    = (ushort*)(ws + 23428992);       //     12,288
    float*  UV      = (float*) (ws + 23441280);       //  6,291,456
    // total 29,732,736 B

    // K_A: all prep (span, transposes, casts, small weights, rlog init)
    prep_all_k<<<3704, 256, 0, stream>>>(seq, spans, W1e, W1r, W2e, W2r, b2r,
                                         erep, erep_bf, W1et, W1rt, W2et, W2rt,
                                         ptab, rlog, seq_bf);
    // K_B: both GEMMs fused (independent): H1bf + UV
    gemm2_k<<<576, 256, 0, stream>>>(seq_bf, W1et, b1e, H1bf, erep_bf, W1rt, UV);
    // K_C: relation_logits + entity_logits fused (independent consumers)
    post_k<<<506, 256, 0, stream>>>(UV, b1r, W2rt, ptab, rlog,
                                    H1bf, W2et, b2e, elog);
}

// Round 10
// 141.322 us; speedup vs baseline: 1.5046x; 1.0643x over previous
//
#include <hip/hip_runtime.h>
#include <hip/hip_bf16.h>

// B=16, S=512, N=64, H=768, E_TYPES=9, R_TYPES=10
// out: entity_logits (73728) | entity_repr (786432) | relation_logits (322560), fp32

#define S_LEN 512
#define H_DIM 768
#define NPAIR 2016

typedef __bf16 bf16x8 __attribute__((ext_vector_type(8)));
typedef float f32x4 __attribute__((ext_vector_type(4)));

__device__ __forceinline__ void gload_lds16(const void* g, void* l) {
    __builtin_amdgcn_global_load_lds(
        (const __attribute__((address_space(1))) void*)g,
        (__attribute__((address_space(3))) void*)l, 16, 0, 0);
}

__device__ __forceinline__ ushort f2bf(float x) {
    __hip_bfloat16 h = __float2bfloat16(x);
    return *(ushort*)&h;
}

// 8 bf16 (16B, aligned) -> 8 f32 via bit ops (exact)
__device__ __forceinline__ void bf8_to_f32(const ushort* p, float* f) {
    const uint* u = (const uint*)p;
    #pragma unroll
    for (int i = 0; i < 4; ++i) {
        uint x = u[i];
        f[2 * i]     = __uint_as_float(x << 16);
        f[2 * i + 1] = __uint_as_float(x & 0xffff0000u);
    }
}

// ---------------------------------------------------------------------------
// K_A: mega prep kernel. blockIdx ranges:
//   [0,1024)      span mean -> erep (fp32) + erep_bf
//   [1024,1312)   trcast W1e (768x384)
//   [1312,1888)   trcast W1r top half (768x768)
//   [1888,2464)   trcast W1r bottom half (768x768)
//   [2464,2542)   W2rt (16x768, pad) + W2et (16x384, pad) + b1r_ext (1536)
//   [2542,3566)   cast seq -> seq_bf (grid-stride float4)
// ---------------------------------------------------------------------------
__global__ __launch_bounds__(256) void prep_all_k(
    const float* __restrict__ seq, const int* __restrict__ spans,
    const float* __restrict__ W1e, const float* __restrict__ W1r,
    const float* __restrict__ W2e, const float* __restrict__ W2r,
    const float* __restrict__ b1r,
    float* __restrict__ erep, ushort* __restrict__ erep_bf,
    ushort* __restrict__ W1et, ushort* __restrict__ W1rt,
    ushort* __restrict__ W2et, ushort* __restrict__ W2rt,
    float* __restrict__ b1r_ext, ushort* __restrict__ seq_bf)
{
    __shared__ float t[32][33];
    const int bid = blockIdx.x, tid = threadIdx.x;

    if (bid < 1024) {
        // ---- span mean ----
        const int bn = bid, b = bn >> 6;
        const int s0 = spans[bn * 2], s1 = spans[bn * 2 + 1];
        int lo = s0 < 0 ? 0 : s0;
        int hi = s1 > S_LEN ? S_LEN : s1;
        int cnt = hi - lo;
        if (cnt < 1) cnt = 1;
        const float inv = 1.f / (float)cnt;
        for (int c = tid; c < H_DIM; c += 256) {
            float acc = 0.f;
            for (int s = lo; s < hi; ++s)
                acc += seq[((size_t)b * S_LEN + s) * H_DIM + c];
            float v = acc * inv;
            erep[(size_t)bn * H_DIM + c] = v;
            erep_bf[(size_t)bn * H_DIM + c] = f2bf(v);
        }
    } else if (bid < 2464) {
        // ---- transpose+cast jobs ----
        const float* src; ushort* dst; int b2, C;
        if (bid < 1312)      { b2 = bid - 1024; src = W1e; dst = W1et; C = 384; }
        else if (bid < 1888) { b2 = bid - 1312; src = W1r; dst = W1rt; C = 768; }
        else                 { b2 = bid - 1888; src = W1r + 768 * 768; dst = W1rt + 768 * 768; C = 768; }
        const int br = b2 % 24, bc = b2 / 24;   // R=768 always -> TR=24
        const int r = tid >> 5, c = tid & 31;
        #pragma unroll
        for (int p = 0; p < 4; ++p) {
            int rr = r + p * 8;
            t[rr][c] = src[(size_t)(br * 32 + rr) * C + bc * 32 + c];
        }
        __syncthreads();
        #pragma unroll
        for (int p = 0; p < 4; ++p) {
            int rr = r + p * 8;
            dst[(size_t)(bc * 32 + rr) * 768 + br * 32 + c] = f2bf(t[c][rr]);
        }
    } else if (bid < 2542) {
        // ---- small weights ----
        int idx = (bid - 2464) * 256 + tid;     // [0, 19968)
        if (idx < 12288) {                       // W2rt[16][768]
            int col = idx / 768, k = idx % 768;
            W2rt[idx] = (col < 10) ? f2bf(W2r[k * 10 + col]) : (ushort)0;
        } else if (idx < 18432) {                // W2et[16][384]
            int u = idx - 12288;
            int col = u / 384, k = u % 384;
            W2et[u] = (col < 9) ? f2bf(W2e[k * 9 + col]) : (ushort)0;
        } else {                                 // b1r_ext[1536]
            int u = idx - 18432;
            b1r_ext[u] = (u < 768) ? b1r[u] : 0.f;
        }
    } else {
        // ---- cast seq -> bf16 ----
        for (int i = (bid - 2542) * 256 + tid; i < (8192 * 768) / 4; i += 1024 * 256) {
            float4 v = ((const float4*)seq)[i];
            ushort4 o;
            o.x = f2bf(v.x); o.y = f2bf(v.y); o.z = f2bf(v.z); o.w = f2bf(v.w);
            ((ushort4*)seq_bf)[i] = o;
        }
    }
}

// ---------------------------------------------------------------------------
// GEMM body: C = A[M,K] @ Bt[N,K]^T, tile 64x128, BK=32, 4 waves (2x2),
// wave tile 32x64 (2x4 frags 16x16x32). 4-deep counted-vmcnt pipeline:
// raw s_barrier (no vmcnt drain) + manual s_waitcnt vmcnt(6/3/0) +
// sched_barrier fence. 3 gload_lds per tile -> steady wait = 3*(D-2) = 6.
// EPI 0: bf16 out = relu(acc + bias[n]);  EPI 2: bf16 out = acc + bias[n].
// ---------------------------------------------------------------------------
template<int EPI>
__device__ __forceinline__ void gemm_body(
    const ushort* __restrict__ A, const ushort* __restrict__ Bt,
    const float* __restrict__ bias, void* __restrict__ Cout,
    int bx, int by, int N, int K, ushort* As, ushort* Bs)
{
    const int tid = threadIdx.x;
    const int lane = tid & 63, wid = tid >> 6;
    const int wr = wid >> 1, wc = wid & 1;
    const int m0 = by * 64, n0 = bx * 128;
    const int fr = lane & 15, kg = lane >> 4;

    const int srow = tid >> 2, skq = (tid & 3) * 8;
    const ushort* ag0 = A + (size_t)(m0 + srow) * K + skq;
    const ushort* bg0 = Bt + (size_t)(n0 + srow) * K + skq;
    const ushort* bg1 = Bt + (size_t)(n0 + 64 + srow) * K + skq;

    int aoff[2], boff[4];
    #pragma unroll
    for (int i = 0; i < 2; ++i)
        aoff[i] = (wr * 32 + i * 16 + fr) * 32 + kg * 8;
    #pragma unroll
    for (int i = 0; i < 4; ++i)
        boff[i] = (wc * 64 + i * 16 + fr) * 32 + kg * 8;

    const int nsteps = K / 32;

    auto STAGE = [&](int kt, int buf) {
        const int kn = kt * 32;
        gload_lds16(ag0 + kn, As + buf * 2048 + tid * 8);
        gload_lds16(bg0 + kn, Bs + buf * 4096 + tid * 8);
        gload_lds16(bg1 + kn, Bs + buf * 4096 + 2048 + tid * 8);
    };

    // prologue: tiles 0,1,2 in flight
    STAGE(0, 0);
    STAGE(1, 1);
    STAGE(2, 2);

    f32x4 acc[2][4] = {};

    for (int t = 0; t < nsteps; ++t) {
        if (t < nsteps - 2)       asm volatile("s_waitcnt vmcnt(6)" ::: "memory");
        else if (t == nsteps - 2) asm volatile("s_waitcnt vmcnt(3)" ::: "memory");
        else                      asm volatile("s_waitcnt vmcnt(0)" ::: "memory");
        __builtin_amdgcn_s_barrier();          // raw: no implicit vmcnt drain
        __builtin_amdgcn_sched_barrier(0);     // fence: nothing hoists above
        if (t + 3 < nsteps) STAGE(t + 3, (t + 3) & 3);
        const int buf = t & 3;
        bf16x8 af[2], bv[4];
        #pragma unroll
        for (int i = 0; i < 2; ++i) af[i] = *(const bf16x8*)&As[buf * 2048 + aoff[i]];
        #pragma unroll
        for (int i = 0; i < 4; ++i) bv[i] = *(const bf16x8*)&Bs[buf * 4096 + boff[i]];
        #pragma unroll
        for (int mi = 0; mi < 2; ++mi)
            #pragma unroll
            for (int nj = 0; nj < 4; ++nj)
                acc[mi][nj] = __builtin_amdgcn_mfma_f32_16x16x32_bf16(
                    af[mi], bv[nj], acc[mi][nj], 0, 0, 0);
    }

    // C/D: col = lane&15, row = (lane>>4)*4 + reg
    __hip_bfloat16* Cb = (__hip_bfloat16*)Cout;
    float bcol[4];
    #pragma unroll
    for (int nj = 0; nj < 4; ++nj) bcol[nj] = bias[n0 + wc * 64 + nj * 16 + fr];
    #pragma unroll
    for (int mi = 0; mi < 2; ++mi)
        #pragma unroll
        for (int j = 0; j < 4; ++j) {
            size_t rb = (size_t)(m0 + wr * 32 + mi * 16 + kg * 4 + j) * N
                      + n0 + wc * 64 + fr;
            #pragma unroll
            for (int nj = 0; nj < 4; ++nj) {
                float v = acc[mi][nj][j] + bcol[nj];
                if (EPI == 0) v = fmaxf(v, 0.f);
                Cb[rb + nj * 16] = __float2bfloat16(v);
            }
        }
}

// ---------------------------------------------------------------------------
// K_B: fused independent GEMMs in one launch.
//   bid [0,384):   H1bf = relu(seq_bf @ W1et^T + b1e)        (8192x384x768)
//   bid [384,576): UVbf = erep_bf @ W1rt^T + b1r_ext (bf16)  (1024x1536x768)
//                  (b1r folded into U columns; V columns +0)
// ---------------------------------------------------------------------------
__global__ __launch_bounds__(256) void gemm2_k(
    const ushort* __restrict__ seq_bf, const ushort* __restrict__ W1et,
    const float* __restrict__ b1e, ushort* __restrict__ H1bf,
    const ushort* __restrict__ erep_bf, const ushort* __restrict__ W1rt,
    const float* __restrict__ b1r_ext, ushort* __restrict__ UVbf)
{
    __shared__ ushort As[4 * 2048];   // 16 KB
    __shared__ ushort Bs[4 * 4096];   // 32 KB
    const int bid = blockIdx.x;
    if (bid < 384) {
        gemm_body<0>(seq_bf, W1et, b1e, H1bf, bid % 3, bid / 3, 384, 768, As, Bs);
    } else {
        const int b2 = bid - 384;
        gemm_body<2>(erep_bf, W1rt, b1r_ext, UVbf, b2 % 12, b2 / 12, 1536, 768, As, Bs);
    }
}

// ---------------------------------------------------------------------------
// K_C: fused consumers in one launch.
//   bid [0,160):   relation logits per (batch, 16x16 pair tile): barrier-free,
//                  LDS-free. U reads wave-uniform (broadcast), V reads 16 rows
//                  x one 64B line per chunk. hidden = relu(Ubf + Vbf) (bias
//                  pre-folded into U), MFMA vs W2rt, direct store + b2r.
//   bid [160,288): entity_logits = H1bf @ W2et^T + b2e (barrier-free MFMA)
// ---------------------------------------------------------------------------
__global__ __launch_bounds__(256) void post_k(
    const ushort* __restrict__ UVbf, const ushort* __restrict__ W2rt,
    const float* __restrict__ b2r, float* __restrict__ rlog,
    const ushort* __restrict__ H1, const ushort* __restrict__ W2et,
    const float* __restrict__ b2e, float* __restrict__ elog)
{
    const int tid = threadIdx.x;
    const int lane = tid & 63, wid = tid >> 6;
    const int fr = lane & 15, kg = lane >> 4;
    const int bid = blockIdx.x;

    if (bid < 160) {
        // ---- relation logits, one (batch, i-tile, j-tile) per block ----
        const int t = bid % 10, b = bid / 10;
        int it, jt;
        if (t < 4)      { it = 0; jt = t; }
        else if (t < 7) { it = 1; jt = t - 3; }
        else if (t < 9) { it = 2; jt = t - 5; }
        else            { it = 3; jt = 3; }
        const int i0 = it * 16, j0 = jt * 16;
        const ushort* Ub = UVbf + (size_t)(b * 64 + i0) * 1536;         // U rows
        const ushort* Vb = UVbf + (size_t)(b * 64 + j0) * 1536 + 768;   // V rows

        f32x4 acc[4] = {};

        for (int c = 0; c < 24; ++c) {
            const int kk = c * 32 + kg * 8;
            const bf16x8 bv = *(const bf16x8*)(W2rt + fr * 768 + kk);
            float fv[8];
            bf8_to_f32(Vb + (size_t)fr * 1536 + kk, fv);   // jj = fr (A-frag row)
            #pragma unroll
            for (int q = 0; q < 4; ++q) {
                float fu[8];
                bf8_to_f32(Ub + (size_t)(wid * 4 + q) * 1536 + kk, fu);  // broadcast
                ushort h[8];
                #pragma unroll
                for (int e = 0; e < 8; ++e)
                    h[e] = f2bf(fmaxf(fu[e] + fv[e], 0.f));
                bf16x8 av = *(bf16x8*)h;
                acc[q] = __builtin_amdgcn_mfma_f32_16x16x32_bf16(av, bv, acc[q], 0, 0, 0);
            }
        }

        // D layout: col = fr (logit), pair-in-frag = kg*4 + jr
        if (fr < 10) {
            const float bias = b2r[fr];
            #pragma unroll
            for (int q = 0; q < 4; ++q) {
                const int i = i0 + wid * 4 + q;
                #pragma unroll
                for (int jr = 0; jr < 4; ++jr) {
                    const int j = j0 + kg * 4 + jr;
                    if (j > i) {
                        int p = i * 63 - i * (i - 1) / 2 + (j - i - 1);
                        rlog[((size_t)(b * NPAIR + p)) * 10 + fr] = acc[q][jr] + bias;
                    }
                }
            }
        }
    } else {
        // ---- entity logits ----
        const int rbase = (bid - 160) * 64 + wid * 16;
        f32x4 acc = {};
        #pragma unroll
        for (int c = 0; c < 12; ++c) {
            const int kk = c * 32 + kg * 8;
            bf16x8 av = *(const bf16x8*)(H1 + (size_t)(rbase + fr) * 384 + kk);
            bf16x8 bv = *(const bf16x8*)(W2et + fr * 384 + kk);
            acc = __builtin_amdgcn_mfma_f32_16x16x32_bf16(av, bv, acc, 0, 0, 0);
        }
        if (fr < 9) {
            const float bias = b2e[fr];
            #pragma unroll
            for (int j = 0; j < 4; ++j)
                elog[(size_t)(rbase + kg * 4 + j) * 9 + fr] = acc[j] + bias;
        }
    }
}

// ---------------------------------------------------------------------------
extern "C" void kernel_launch(void* const* d_in, const int* in_sizes, int n_in,
                              void* d_out, int out_size, void* d_ws, size_t ws_size,
                              hipStream_t stream)
{
    const float* seq   = (const float*)d_in[0];
    const int*   spans = (const int*)d_in[2];
    const float* W1e   = (const float*)d_in[3];
    const float* b1e   = (const float*)d_in[4];
    const float* W2e   = (const float*)d_in[5];
    const float* b2e   = (const float*)d_in[6];
    const float* W1r   = (const float*)d_in[7];
    const float* b1r   = (const float*)d_in[8];
    const float* W2r   = (const float*)d_in[9];
    const float* b2r   = (const float*)d_in[10];

    float* out  = (float*)d_out;
    float* elog = out;
    float* erep = out + 73728;
    float* rlog = out + 73728 + 786432;

    // ws layout (all rewritten every launch; poison-safe)
    char* ws = (char*)d_ws;
    ushort* seq_bf  = (ushort*)ws;                    // 12,582,912
    ushort* W1et    = (ushort*)(ws + 12582912);       //    589,824
    ushort* W1rt    = (ushort*)(ws + 13172736);       //  2,359,296
    ushort* erep_bf = (ushort*)(ws + 15532032);       //  1,572,864
    ushort* H1bf    = (ushort*)(ws + 17104896);       //  6,291,456
    ushort* W2rt    = (ushort*)(ws + 23396352);       //     24,576
    ushort* W2et    = (ushort*)(ws + 23420928);       //     12,288
    float*  b1r_ext = (float*) (ws + 23433216);       //      6,144
    ushort* UVbf    = (ushort*)(ws + 23439360);       //  3,145,728
    // total 26,585,088 B

    // K_A: all prep (span, transposes, casts, small weights)
    prep_all_k<<<3566, 256, 0, stream>>>(seq, spans, W1e, W1r, W2e, W2r, b1r,
                                         erep, erep_bf, W1et, W1rt, W2et, W2rt,
                                         b1r_ext, seq_bf);
    // K_B: both GEMMs fused (independent): H1bf + UVbf
    gemm2_k<<<576, 256, 0, stream>>>(seq_bf, W1et, b1e, H1bf,
                                     erep_bf, W1rt, b1r_ext, UVbf);
    // K_C: relation_logits + entity_logits fused (independent consumers)
    post_k<<<288, 256, 0, stream>>>(UVbf, W2rt, b2r, rlog,
                                    H1bf, W2et, b2e, elog);
}